// Round 5
// baseline (143.924 us; speedup 1.0000x reference)
//
#include <hip/hip_runtime.h>
#include <hip/hip_bf16.h>
#include <math.h>

#define Bb 2
#define Nn 2048
#define Ee 256
#define Hh 4
#define DKk 64

typedef __bf16 bf16x8 __attribute__((ext_vector_type(8)));
typedef float f32x4 __attribute__((ext_vector_type(4)));

// QSCALE = (1/sqrt(64)) * log2(e): folded into Wq so scores come out of the
// MFMA already in exp2 domain. MOFF folded into MFMA C init (free subtract).
#define QSCALE 0.18033688011112042f
#define MOFF 20.0f

// ---------------- merged pack: adjacency bits + weights ----------------
// blk < 2048: adj -> bits. Group = 256 keys -> 4 u64 words; word c, bit l
//   <-> key 4*l + c (attn lane li reads word li&3, bit for key k at pos k>>2).
// 2048..2815: WB rows (Wq pre-scaled by QSCALE). >=2816: WoB.
__global__ void __launch_bounds__(256) pack_kernel(
        const int* __restrict__ adj,
        const float* __restrict__ Wq,
        const float* __restrict__ Wk,
        const float* __restrict__ Wv,
        const float* __restrict__ Wo,
        unsigned long long* __restrict__ bits,
        __bf16* __restrict__ WB,
        __bf16* __restrict__ WoB) {
    int blk = blockIdx.x, t = threadIdx.x;
    if (blk < 2048) {
        int wid = t >> 6, lane = t & 63;
        #pragma unroll
        for (int i = 0; i < 4; ++i) {
            int gid = blk * 16 + i * 4 + wid;          // 0..32767
            int row = gid >> 3;                        // b*N + q
            int g = gid & 7;                           // 256-key group
            const int4* src = (const int4*)(adj + (size_t)row * Nn + g * 256) + lane;
            int4 v = *src;
            unsigned long long b0 = __ballot(v.x > 0);
            unsigned long long b1 = __ballot(v.y > 0);
            unsigned long long b2 = __ballot(v.z > 0);
            unsigned long long b3 = __ballot(v.w > 0);
            if (lane == 0) {
                ulonglong2* dst = (ulonglong2*)(bits + (size_t)gid * 4);
                ulonglong2 p0; p0.x = b0; p0.y = b1;
                ulonglong2 p1; p1.x = b2; p1.y = b3;
                dst[0] = p0;
                dst[1] = p1;
            }
        }
    } else if (blk < 2816) {
        int row = blk - 2048;              // (m*4+h)*64 + e
        int m = row >> 8, h = (row >> 6) & 3, e = row & 63;
        const float* W = (m == 0 ? Wq : (m == 1 ? Wk : Wv));
        float sc = (m == 0) ? QSCALE : 1.0f;
        WB[(size_t)row * 256 + t] = (__bf16)(W[h * 16384 + t * 64 + e] * sc);
    } else {
        int blk2 = blk - 2816;             // 0..63
        size_t i = ((size_t)blk2 * 256 + t) * 4;
        float4 v = *(const float4*)(Wo + i);
        __bf16 o[4] = {(__bf16)v.x, (__bf16)v.y, (__bf16)v.z, (__bf16)v.w};
        *(ushort4*)(WoB + i) = *(ushort4*)o;
    }
}

// ---------------- QKV projection via MFMA (x converted inline) ----------------
// x:(4096,256) fp32 @ WB(768,256)^T. Q -> row-major (bh,n,dk).
// K -> Kf fragment order, V -> Vf fragment order (see attn loads).
__global__ void __launch_bounds__(256) qkv_mfma(
        const float* __restrict__ x,
        const __bf16* __restrict__ WB,
        __bf16* __restrict__ Qb,
        __bf16* __restrict__ Kf,
        __bf16* __restrict__ Vf) {
    int bm = blockIdx.x;                 // 256 blocks, rows bm*16..+15
    int t = threadIdx.x;
    int wid = t >> 6, lane = t & 63, li = lane & 15, quad = lane >> 4;
    int row0 = bm * 16;

    bf16x8 a[8];
    const float* xp = x + (size_t)(row0 + li) * 256 + quad * 8;
    #pragma unroll
    for (int i = 0; i < 8; ++i) {
        float4 f0 = *(const float4*)(xp + i * 32);
        float4 f1 = *(const float4*)(xp + i * 32 + 4);
        __bf16 tmp[8] = {(__bf16)f0.x, (__bf16)f0.y, (__bf16)f0.z, (__bf16)f0.w,
                         (__bf16)f1.x, (__bf16)f1.y, (__bf16)f1.z, (__bf16)f1.w};
        a[i] = *(bf16x8*)tmp;
    }

    int b = row0 >> 11;
    int nloc = row0 & 2047;

    #pragma unroll 1
    for (int j = 0; j < 12; ++j) {
        int c0 = wid * 192 + j * 16;
        const __bf16* bp = WB + (size_t)(c0 + li) * 256 + quad * 8;
        f32x4 acc = (f32x4){0.f, 0.f, 0.f, 0.f};
        #pragma unroll
        for (int i = 0; i < 8; ++i) {
            bf16x8 bfrag = *(const bf16x8*)(bp + i * 32);
            acc = __builtin_amdgcn_mfma_f32_16x16x32_bf16(a[i], bfrag, acc, 0, 0, 0);
        }
        int m = c0 >> 8;                  // wave-uniform
        int h = (c0 >> 6) & 3;
        int e0 = c0 & 63;
        int bh = b * 4 + h;
        if (m == 0) {
            size_t base = ((size_t)bh * Nn + nloc + quad * 4) * 64 + e0 + li;
            #pragma unroll
            for (int r = 0; r < 4; ++r) Qb[base + (size_t)r * 64] = (__bf16)acc[r];
        } else if (m == 1) {
            int e = e0 + li;
            int cp = e >> 5, ek = e & 31;
            int qA = ek >> 3, jA = ek & 7;
            int kt = nloc >> 4;
            size_t ub = (((size_t)(bh * 128 + kt)) * 2 + cp) * 512 + qA * 128 + jA;
            #pragma unroll
            for (int r = 0; r < 4; ++r) Kf[ub + (quad * 4 + r) * 8] = (__bf16)acc[r];
        } else {
            int e = e0 + li;
            int et = e >> 4, liA = e & 15;
            int key32 = nloc >> 5;
            int nnb = nloc & 16;
            size_t ub = (((size_t)(bh * 64 + key32)) * 4 + et) * 512 + liA * 8;
            #pragma unroll
            for (int r = 0; r < 4; ++r) {
                int nn = nnb + quad * 4 + r;
                Vf[ub + (nn >> 3) * 128 + (nn & 7)] = (__bf16)acc[r];
            }
        }
    }
}

// ---------------- flash attention: static-max softmax, frag-ordered K/V ----------------
// Grid: bh(8) x qt(128) = 1024 blocks = 4/CU co-resident. 4 waves; wave w
// owns key quarter w (tiles 8w..8w+7).
__global__ void __launch_bounds__(256, 4) attn_kernel(
        const __bf16* __restrict__ Qb,
        const __bf16* __restrict__ Kf,
        const __bf16* __restrict__ Vf,
        const unsigned long long* __restrict__ bits,
        __bf16* __restrict__ heads) {
    __shared__ __align__(16) __bf16 PS[4][16][72];
    __shared__ float OL[4][16][68];
    __shared__ float lL[4][16];

    int blk = blockIdx.x;
    int bh = blk >> 7, qt = blk & 127;
    int b = bh >> 2, h = bh & 3;
    int t = threadIdx.x;
    int wid = t >> 6, lane = t & 63, li = lane & 15, quad = lane >> 4;
    int li2 = li >> 2;
    int q0 = qt * 16;

    const __bf16* qp = Qb + ((size_t)bh * Nn + q0 + li) * 64 + quad * 8;
    bf16x8 qa0 = *(const bf16x8*)qp;
    bf16x8 qa1 = *(const bf16x8*)(qp + 32);

    f32x4 o[4];
    #pragma unroll
    for (int et = 0; et < 4; ++et) o[et] = (f32x4){0.f, 0.f, 0.f, 0.f};
    f32x4 ls = (f32x4){0.f, 0.f, 0.f, 0.f};

    const __bf16* Kfb = Kf + (size_t)bh * 131072;
    const __bf16* Vfb = Vf + (size_t)bh * 131072;
    int lanew = lane * 8;

    #pragma unroll 1
    for (int g = 0; g < 2; ++g) {
        int grp = wid * 2 + g;                       // 256-key group 0..7
        unsigned long long aw[4];
        #pragma unroll
        for (int r = 0; r < 4; ++r)
            aw[r] = bits[(((size_t)b * Nn + q0 + quad * 4 + r) * 8 + grp) * 4 + (li & 3)];

        #pragma unroll 1
        for (int tt = 0; tt < 4; ++tt) {
            int key64 = grp * 4 + tt;                // 64-key tile 0..31

            bf16x8 kb[4][2];
            #pragma unroll
            for (int nt = 0; nt < 4; ++nt)
                #pragma unroll
                for (int c = 0; c < 2; ++c)
                    kb[nt][c] = *(const bf16x8*)(Kfb + ((size_t)((key64 * 4 + nt) * 2 + c)) * 512 + lanew);
            bf16x8 vb[4][2];
            #pragma unroll
            for (int et = 0; et < 4; ++et)
                #pragma unroll
                for (int kc = 0; kc < 2; ++kc)
                    vb[et][kc] = *(const bf16x8*)(Vfb + ((size_t)((key64 * 2 + kc) * 4 + et)) * 512 + lanew);

            f32x4 s[4];
            #pragma unroll
            for (int nt = 0; nt < 4; ++nt) {
                f32x4 z = (f32x4){-MOFF, -MOFF, -MOFF, -MOFF};
                z = __builtin_amdgcn_mfma_f32_16x16x32_bf16(qa0, kb[nt][0], z, 0, 0, 0);
                s[nt] = __builtin_amdgcn_mfma_f32_16x16x32_bf16(qa1, kb[nt][1], z, 0, 0, 0);
            }

            // one u32 half-extract per row, then bfe+cndmask per element
            unsigned halfw[4];
            #pragma unroll
            for (int r = 0; r < 4; ++r) halfw[r] = (unsigned)(aw[r] >> (tt * 16));
            #pragma unroll
            for (int nt = 0; nt < 4; ++nt) {
                #pragma unroll
                for (int r = 0; r < 4; ++r) {
                    unsigned bit = (halfw[r] >> (li2 + nt * 4)) & 1u;
                    float p = bit ? __builtin_amdgcn_exp2f(s[nt][r]) : 0.f;
                    ls[r] += p;
                    PS[wid][quad * 4 + r][nt * 16 + li] = (__bf16)p;
                }
            }

            bf16x8 pa0 = *(const bf16x8*)&PS[wid][li][quad * 8];
            bf16x8 pa1 = *(const bf16x8*)&PS[wid][li][quad * 8 + 32];

            #pragma unroll
            for (int et = 0; et < 4; ++et) {
                o[et] = __builtin_amdgcn_mfma_f32_16x16x32_bf16(pa0, vb[et][0], o[et], 0, 0, 0);
                o[et] = __builtin_amdgcn_mfma_f32_16x16x32_bf16(pa1, vb[et][1], o[et], 0, 0, 0);
            }
        }
    }

    // per-wave epilogue: reduce l across the 16 li lanes, stash o + l in LDS
    #pragma unroll
    for (int r = 0; r < 4; ++r) {
        float v = ls[r];
        v += __shfl_xor(v, 1, 64);
        v += __shfl_xor(v, 2, 64);
        v += __shfl_xor(v, 4, 64);
        v += __shfl_xor(v, 8, 64);
        if (li == 0) lL[wid][quad * 4 + r] = v;
        #pragma unroll
        for (int et = 0; et < 4; ++et)
            OL[wid][quad * 4 + r][et * 16 + li] = o[et][r];
    }
    __syncthreads();

    // merge the 4 key quarters: pure sums (static offset shared by all waves)
    int qi = t >> 4, e0 = (t & 15) * 4;
    float l = lL[0][qi] + lL[1][qi] + lL[2][qi] + lL[3][qi];
    float inv = 1.0f / l;
    float s0 = 0.f, s1 = 0.f, s2 = 0.f, s3 = 0.f;
    #pragma unroll
    for (int w = 0; w < 4; ++w) {
        s0 += OL[w][qi][e0];
        s1 += OL[w][qi][e0 + 1];
        s2 += OL[w][qi][e0 + 2];
        s3 += OL[w][qi][e0 + 3];
    }
    __bf16 ob[4] = {(__bf16)(s0 * inv), (__bf16)(s1 * inv),
                    (__bf16)(s2 * inv), (__bf16)(s3 * inv)};
    __bf16* dst = heads + ((size_t)b * Nn + q0 + qi) * 256 + h * 64 + e0;
    *(ushort4*)dst = *(ushort4*)ob;
}

// ---------------- output projection via MFMA: out = heads @ Wo^T + bo ----------------
__global__ void __launch_bounds__(256) outproj_mfma(
        const __bf16* __restrict__ hb,
        const __bf16* __restrict__ WoB,
        const float* __restrict__ bo,
        float* __restrict__ out) {
    int bm = blockIdx.x;                 // 256 blocks, rows bm*16..+15
    int t = threadIdx.x;
    int wid = t >> 6, lane = t & 63, li = lane & 15, quad = lane >> 4;
    int row0 = bm * 16;

    bf16x8 a[8];
    const __bf16* ap = hb + (size_t)(row0 + li) * 256 + quad * 8;
    #pragma unroll
    for (int i = 0; i < 8; ++i) a[i] = *(const bf16x8*)(ap + i * 32);

    #pragma unroll 1
    for (int j = 0; j < 4; ++j) {
        int c0 = wid * 64 + j * 16;
        const __bf16* bp = WoB + (size_t)(c0 + li) * 256 + quad * 8;
        f32x4 acc = (f32x4){0.f, 0.f, 0.f, 0.f};
        #pragma unroll
        for (int i = 0; i < 8; ++i) {
            bf16x8 bfrag = *(const bf16x8*)(bp + i * 32);
            acc = __builtin_amdgcn_mfma_f32_16x16x32_bf16(a[i], bfrag, acc, 0, 0, 0);
        }
        int c = c0 + li;
        float bias = bo[c];
        size_t base = ((size_t)row0 + quad * 4) * 256 + c;
        #pragma unroll
        for (int r = 0; r < 4; ++r) out[base + (size_t)r * 256] = acc[r] + bias;
    }
}

extern "C" void kernel_launch(void* const* d_in, const int* in_sizes, int n_in,
                              void* d_out, int out_size, void* d_ws, size_t ws_size,
                              hipStream_t stream) {
    const float* x   = (const float*)d_in[0];
    const int*   adj = (const int*)d_in[1];
    const float* Wq  = (const float*)d_in[2];
    const float* Wk  = (const float*)d_in[3];
    const float* Wv  = (const float*)d_in[4];
    const float* Wo  = (const float*)d_in[5];
    const float* bo  = (const float*)d_in[6];
    float* out = (float*)d_out;

    char* ws = (char*)d_ws;
    const size_t MB = 1024 * 1024;
    __bf16* Qb  = (__bf16*)(ws);                         // 0-2 MB
    __bf16* Kf  = (__bf16*)(ws + 2 * MB);                // 2-4 MB
    __bf16* Vf  = (__bf16*)(ws + 4 * MB);                // 4-6 MB
    unsigned long long* bits = (unsigned long long*)(ws + 6 * MB);  // 6-7 MB
    __bf16* WB  = (__bf16*)(ws + 7 * MB);                // 384 KB
    __bf16* WoB = (__bf16*)(ws + 7 * MB + 512 * 1024);   // 128 KB
    __bf16* headsb = (__bf16*)(ws + 8 * MB);             // 8-10 MB

    pack_kernel<<<2880, 256, 0, stream>>>(adj, Wq, Wk, Wv, Wo, bits, WB, WoB);
    qkv_mfma<<<256, 256, 0, stream>>>(x, WB, Qb, Kf, Vf);
    attn_kernel<<<Bb * Hh * (Nn / 16), 256, 0, stream>>>(Qb, Kf, Vf, bits, headsb);
    outproj_mfma<<<256, 256, 0, stream>>>(headsb, WoB, bo, out);
}